// Round 2
// baseline (198.697 us; speedup 1.0000x reference)
//
#include <hip/hip_runtime.h>

#define NC 32     // num_capsule
#define DC 16     // dim_capsule
#define INC 144   // input capsules
#define IND 8     // input dim
#define NT 1024   // threads per block
#define A2 2      // batch elements per block

// LDS (halves): hat[32][2320] | lg[32][152] (x[2][144][8] overlaps, dead after H) | o_h[32][16]
#define HAT_BS 2320   // 1160 dwords == 8 mod 32 -> b-groups on disjoint bank octets
#define LG_S 152      // 304 B per b, 16B-aligned
#define HAT_HALVES (NC * HAT_BS)        // 74240
#define LG_OFF HAT_HALVES
#define OH_OFF (LG_OFF + NC * LG_S)     // 79104
#define SMEM_HALVES (OH_OFF + NC * DC)  // 79616
#define SMEM_BYTES (SMEM_HALVES * 2)    // 159232 <= 163840

typedef _Float16 h2 __attribute__((ext_vector_type(2)));
typedef _Float16 h4 __attribute__((ext_vector_type(4)));
typedef _Float16 h8 __attribute__((ext_vector_type(8)));
typedef float f4 __attribute__((ext_vector_type(4)));

union H8 { h8 v; h2 p[4]; };

#if __has_builtin(__builtin_amdgcn_fdot2)
__device__ __forceinline__ float fdot2(h2 a, h2 b, float c) {
    return __builtin_amdgcn_fdot2(a, b, c, false);
}
#else
__device__ __forceinline__ float fdot2(h2 a, h2 b, float c) {
    return c + (float)a[0] * (float)b[0] + (float)a[1] * (float)b[1];
}
#endif

__global__ void convw_kernel(const float* __restrict__ W, _Float16* __restrict__ Wh) {
    int i = blockIdx.x * 256 + threadIdx.x;  // 147456 f4 groups
    f4 v = reinterpret_cast<const f4*>(W)[i];
    h4 h;
    h[0] = (_Float16)v[0]; h[1] = (_Float16)v[1];
    h[2] = (_Float16)v[2]; h[3] = (_Float16)v[3];
    reinterpret_cast<h4*>(Wh)[i] = h;
}

__device__ __forceinline__ float squash16(float s) {
    float n2 = s * s;
    n2 += __shfl_xor(n2, 1, 16);
    n2 += __shfl_xor(n2, 2, 16);
    n2 += __shfl_xor(n2, 4, 16);
    n2 += __shfl_xor(n2, 8, 16);
    return s * (n2 / ((1.0f + n2) * sqrtf(n2 + 1e-7f)));
}

template <typename WT>
__global__ __launch_bounds__(NT)
void caps_kernel(const float* __restrict__ xg, const WT* __restrict__ Wg,
                 float* __restrict__ out) {
    extern __shared__ _Float16 sm[];
    _Float16* hat = sm;
    _Float16* lg = sm + LG_OFF;
    _Float16* o_h = sm + OH_OFF;
    _Float16* x_h = lg;  // overlap: x dead after phase H

    const int t = threadIdx.x;
    const int a2 = t >> 9;        // which batch element this thread owns
    const int b = (t >> 4) & 31;  // capsule
    const int d = t & 15;         // dim (also 'j' in B-pass)
    const int a = blockIdx.x * A2 + a2;

    // ---- load x for 2 batch elems: 2304 floats = 576 f4, convert to fp16 ----
    if (t < 576) {
        f4 v = reinterpret_cast<const f4*>(xg + (size_t)blockIdx.x * (A2 * INC * IND))[t];
        h4 h;
        h[0] = (_Float16)v[0]; h[1] = (_Float16)v[1];
        h[2] = (_Float16)v[2]; h[3] = (_Float16)v[3];
        *reinterpret_cast<h4*>(x_h + t * 4) = h;
    }
    __syncthreads();

    // ---- Phase H: hat[b][c][d] into REGISTERS (72 half2), + s0 ----
    h2 hreg[72];
    float s0a = 0.f, s0b = 0.f;
    {
        const WT* wp = Wg + ((size_t)(b * INC) * DC + d) * IND;
        const _Float16* xp = x_h + a2 * (INC * IND);
        #pragma unroll
        for (int c = 0; c < INC; ++c) {
            H8 xv;
            xv.v = *reinterpret_cast<const h8*>(xp + c * IND);
            float acc;
            if constexpr (sizeof(WT) == 2) {
                H8 wv;
                wv.v = *reinterpret_cast<const h8*>(wp + (size_t)c * (DC * IND));
                acc = fdot2(wv.p[0], xv.p[0], 0.f);
                acc = fdot2(wv.p[1], xv.p[1], acc);
                acc = fdot2(wv.p[2], xv.p[2], acc);
                acc = fdot2(wv.p[3], xv.p[3], acc);
            } else {
                const float* wf = reinterpret_cast<const float*>(wp) + (size_t)c * (DC * IND);
                f4 w0 = *reinterpret_cast<const f4*>(wf);
                f4 w1 = *reinterpret_cast<const f4*>(wf + 4);
                acc = (float)xv.v[0] * w0[0];
                acc = fmaf((float)xv.v[1], w0[1], acc);
                acc = fmaf((float)xv.v[2], w0[2], acc);
                acc = fmaf((float)xv.v[3], w0[3], acc);
                acc = fmaf((float)xv.v[4], w1[0], acc);
                acc = fmaf((float)xv.v[5], w1[1], acc);
                acc = fmaf((float)xv.v[6], w1[2], acc);
                acc = fmaf((float)xv.v[7], w1[3], acc);
            }
            if (c & 1) s0b += acc; else s0a += acc;
            hreg[c >> 1][c & 1] = (_Float16)acc;  // RN convert, single source of truth
        }
    }
    float ocur;
    {
        float s0 = (s0a + s0b) * (1.0f / 32.0f);  // softmax(0) uniform
        ocur = squash16(s0);
    }

    // ---- route each batch element in turn; all 1024 threads help ----
    for (int aa = 0; aa < A2; ++aa) {
        if (a2 == aa) {
            // publish my hat rows + initial o to LDS
            _Float16* hp = hat + b * HAT_BS + d;
            #pragma unroll
            for (int c = 0; c < INC; ++c) hp[c * DC] = hreg[c >> 1][c & 1];
            o_h[b * DC + d] = (_Float16)ocur;
        }
        __syncthreads();

        float lgr[5];  // fp32 logit master; c = d + 16*(2k + a2)
        #pragma unroll
        for (int k = 0; k < 5; ++k) lgr[k] = 0.f;

        for (int it = 0; it < 2; ++it) {
            // ---- B-pass (all threads): logit[b][c] += o[b,:] . hat[b][c][:] ----
            {
                H8 o0, o1;
                o0.v = *reinterpret_cast<const h8*>(o_h + b * DC);
                o1.v = *reinterpret_cast<const h8*>(o_h + b * DC + 8);
                #pragma unroll
                for (int k = 0; k < 5; ++k) {
                    int c = d + DC * (2 * k + a2);
                    if (c < INC) {  // wave-uniform (a2 uniform per wave)
                        const _Float16* hp = hat + b * HAT_BS + c * DC;
                        H8 h0, h1;
                        h0.v = *reinterpret_cast<const h8*>(hp);
                        h1.v = *reinterpret_cast<const h8*>(hp + 8);
                        float dot = fdot2(h0.p[0], o0.p[0], 0.f);
                        dot = fdot2(h0.p[1], o0.p[1], dot);
                        dot = fdot2(h0.p[2], o0.p[2], dot);
                        dot = fdot2(h0.p[3], o0.p[3], dot);
                        dot = fdot2(h1.p[0], o1.p[0], dot);
                        dot = fdot2(h1.p[1], o1.p[1], dot);
                        dot = fdot2(h1.p[2], o1.p[2], dot);
                        dot = fdot2(h1.p[3], o1.p[3], dot);
                        lgr[k] += dot;
                        lg[b * LG_S + c] = (_Float16)lgr[k];
                    }
                }
            }
            __syncthreads();

            // ---- softmax over 32 capsules, one thread per c (3-pass, no reg spike) ----
            if (t < INC) {
                const int c = t;
                float m = -1e30f;
                for (int bb = 0; bb < NC; ++bb)
                    m = fmaxf(m, (float)lg[bb * LG_S + c]);
                float S = 0.f;
                for (int bb = 0; bb < NC; ++bb) {
                    float e = __expf((float)lg[bb * LG_S + c] - m);
                    S += e;
                    lg[bb * LG_S + c] = (_Float16)e;
                }
                float inv = 1.0f / S;
                for (int bb = 0; bb < NC; ++bb)
                    lg[bb * LG_S + c] = (_Float16)((float)lg[bb * LG_S + c] * inv);
            }
            __syncthreads();

            // ---- S-pass (owning threads, from registers): s = sum_c cc[b][c]*hat[c] ----
            if (a2 == aa) {
                const _Float16* cp = lg + b * LG_S;
                float sA = 0.f, sB = 0.f;
                #pragma unroll
                for (int m2 = 0; m2 < 18; ++m2) {
                    H8 cc;
                    cc.v = *reinterpret_cast<const h8*>(cp + m2 * 8);
                    sA = fdot2(cc.p[0], hreg[m2 * 4 + 0], sA);
                    sB = fdot2(cc.p[1], hreg[m2 * 4 + 1], sB);
                    sA = fdot2(cc.p[2], hreg[m2 * 4 + 2], sA);
                    sB = fdot2(cc.p[3], hreg[m2 * 4 + 3], sB);
                }
                float oo = squash16(sA + sB);
                if (it == 0) o_h[b * DC + d] = (_Float16)oo;
                else out[(size_t)a * (NC * DC) + b * DC + d] = oo;
            }
            __syncthreads();
        }
    }
}

extern "C" void kernel_launch(void* const* d_in, const int* in_sizes, int n_in,
                              void* d_out, int out_size, void* d_ws, size_t ws_size,
                              hipStream_t stream) {
    const float* x = (const float*)d_in[0];
    const float* W = (const float*)d_in[1];
    float* out = (float*)d_out;

    const size_t WH_BYTES = (size_t)NC * INC * DC * IND * 2;  // 1179648

    if (ws_size >= WH_BYTES) {
        _Float16* Wh = (_Float16*)d_ws;
        hipLaunchKernelGGL(convw_kernel, dim3((NC * INC * DC * IND / 4) / 256),
                           dim3(256), 0, stream, W, Wh);
        hipFuncSetAttribute(reinterpret_cast<const void*>(&caps_kernel<_Float16>),
                            hipFuncAttributeMaxDynamicSharedMemorySize, SMEM_BYTES);
        hipLaunchKernelGGL(caps_kernel<_Float16>, dim3(512 / A2), dim3(NT), SMEM_BYTES,
                           stream, x, Wh, out);
    } else {
        hipFuncSetAttribute(reinterpret_cast<const void*>(&caps_kernel<float>),
                            hipFuncAttributeMaxDynamicSharedMemorySize, SMEM_BYTES);
        hipLaunchKernelGGL(caps_kernel<float>, dim3(512 / A2), dim3(NT), SMEM_BYTES,
                           stream, x, W, out);
    }
}

// Round 4
// 75.968 us; speedup vs baseline: 2.6156x; 2.6156x over previous
//
#include <hip/hip_runtime.h>

#define NC 32     // num_capsule
#define DC 16     // dim_capsule
#define INC 144   // input capsules
#define IND 8     // input dim
#define NT 512    // threads per block
#define A2 2      // batch elements per block (share the W stream)

// LDS (halves): hat[32][2320] | lg[32][152] (x[2][144][8] fp16 overlaps, dead after H) | o_h[32][16]
#define HAT_BS 2320   // 1160 dwords == 8 mod 32 -> wave's 4 b-groups on disjoint bank octets
#define LG_S 152      // 76 dwords == 12 mod 32 -> 4 rows read per wave land on distinct quads
#define LG_OFF (NC * HAT_BS)
#define OH_OFF (LG_OFF + NC * LG_S)      // 79104
#define SMEM_HALVES (OH_OFF + NC * DC)   // 79616
#define SMEM_BYTES (SMEM_HALVES * 2)     // 159232 <= 163840

typedef _Float16 h2 __attribute__((ext_vector_type(2)));
typedef _Float16 h4 __attribute__((ext_vector_type(4)));
typedef _Float16 h8 __attribute__((ext_vector_type(8)));
typedef float f4 __attribute__((ext_vector_type(4)));

union H8 { h8 v; h2 p[4]; };

#if __has_builtin(__builtin_amdgcn_fdot2)
__device__ __forceinline__ float fdot2(h2 a, h2 b, float c) {
    return __builtin_amdgcn_fdot2(a, b, c, false);
}
#else
__device__ __forceinline__ float fdot2(h2 a, h2 b, float c) {
    return c + (float)a[0] * (float)b[0] + (float)a[1] * (float)b[1];
}
#endif

__global__ void convw_kernel(const float* __restrict__ W, _Float16* __restrict__ Wh) {
    int i = blockIdx.x * 256 + threadIdx.x;  // 147456 f4 groups
    f4 v = reinterpret_cast<const f4*>(W)[i];
    h4 h;
    h[0] = (_Float16)v[0]; h[1] = (_Float16)v[1];
    h[2] = (_Float16)v[2]; h[3] = (_Float16)v[3];
    reinterpret_cast<h4*>(Wh)[i] = h;
}

__device__ __forceinline__ float squash16(float s) {
    float n2 = s * s;
    n2 += __shfl_xor(n2, 1, 16);
    n2 += __shfl_xor(n2, 2, 16);
    n2 += __shfl_xor(n2, 4, 16);
    n2 += __shfl_xor(n2, 8, 16);
    return s * (n2 / ((1.0f + n2) * sqrtf(n2 + 1e-7f)));
}

// Routing for ONE batch element; hat fragments come from registers (hreg),
// the LDS hat copy serves only the B-pass. All hreg indices compile-time.
__device__ __forceinline__ void route_one(const h2 (&hreg)[72], float ocur,
                                          _Float16* hat, _Float16* lg, _Float16* o_h,
                                          float* __restrict__ out, int aout,
                                          int t, int b, int d) {
    // publish my (b,d) hat row + initial o to LDS
    {
        _Float16* hp = hat + b * HAT_BS + d;
        #pragma unroll
        for (int c = 0; c < INC; ++c) hp[c * DC] = hreg[c >> 1][c & 1];
        o_h[t] = (_Float16)ocur;
    }
    __syncthreads();

    float lgr[9] = {0.f, 0.f, 0.f, 0.f, 0.f, 0.f, 0.f, 0.f, 0.f};  // fp32 logit master

    for (int it = 0; it < 2; ++it) {
        // ---- B-pass: logit[b][c] += o[b,:] . hat[b][c][:], c = d + 16k ----
        {
            H8 o0, o1;
            o0.v = *reinterpret_cast<const h8*>(o_h + b * DC);
            o1.v = *reinterpret_cast<const h8*>(o_h + b * DC + 8);
            #pragma unroll
            for (int k = 0; k < 9; ++k) {
                const int c = d + DC * k;
                const _Float16* hp = hat + b * HAT_BS + c * DC;
                H8 h0, h1;
                h0.v = *reinterpret_cast<const h8*>(hp);
                h1.v = *reinterpret_cast<const h8*>(hp + 8);
                float dot = fdot2(h0.p[0], o0.p[0], 0.f);
                dot = fdot2(h0.p[1], o0.p[1], dot);
                dot = fdot2(h0.p[2], o0.p[2], dot);
                dot = fdot2(h0.p[3], o0.p[3], dot);
                dot = fdot2(h1.p[0], o1.p[0], dot);
                dot = fdot2(h1.p[1], o1.p[1], dot);
                dot = fdot2(h1.p[2], o1.p[2], dot);
                dot = fdot2(h1.p[3], o1.p[3], dot);
                lgr[k] += dot;
                lg[b * LG_S + c] = (_Float16)lgr[k];
            }
        }
        __syncthreads();

        // ---- softmax over 32 capsules, one thread per input capsule c ----
        if (t < INC) {
            const int c = t;
            float m = -1e30f;
            for (int bb = 0; bb < NC; ++bb)
                m = fmaxf(m, (float)lg[bb * LG_S + c]);
            float S = 0.f;
            for (int bb = 0; bb < NC; ++bb) {
                float e = __expf((float)lg[bb * LG_S + c] - m);
                S += e;
                lg[bb * LG_S + c] = (_Float16)e;
            }
            float inv = 1.0f / S;
            for (int bb = 0; bb < NC; ++bb)
                lg[bb * LG_S + c] = (_Float16)((float)lg[bb * LG_S + c] * inv);
        }
        __syncthreads();

        // ---- S-pass from registers: s = sum_c cc[b][c] * hat[c][d] ----
        {
            const _Float16* cp = lg + b * LG_S;
            float sA = 0.f, sB = 0.f;
            #pragma unroll
            for (int m2 = 0; m2 < 18; ++m2) {
                H8 cc;
                cc.v = *reinterpret_cast<const h8*>(cp + m2 * 8);
                sA = fdot2(cc.p[0], hreg[m2 * 4 + 0], sA);
                sB = fdot2(cc.p[1], hreg[m2 * 4 + 1], sB);
                sA = fdot2(cc.p[2], hreg[m2 * 4 + 2], sA);
                sB = fdot2(cc.p[3], hreg[m2 * 4 + 3], sB);
            }
            float oo = squash16(sA + sB);
            if (it == 0) {
                o_h[t] = (_Float16)oo;
            } else {
                out[(size_t)aout * (NC * DC) + t] = oo;
            }
        }
        if (it == 0) __syncthreads();
    }
}

template <typename WT>
__global__ __launch_bounds__(NT, 2)
void caps_kernel(const float* __restrict__ xg, const WT* __restrict__ Wg,
                 float* __restrict__ out) {
    extern __shared__ _Float16 sm[];
    _Float16* hat = sm;
    _Float16* lg = sm + LG_OFF;
    _Float16* o_h = sm + OH_OFF;
    _Float16* x_h = lg;  // overlap: x only live during phase H

    const int t = threadIdx.x;
    const int b = t >> 4;   // capsule
    const int d = t & 15;   // dim

    // ---- load x for 2 batch elems: 2304 floats = 576 f4, convert fp16 ----
    for (int i = t; i < (A2 * INC * IND) / 4; i += NT) {
        f4 v = reinterpret_cast<const f4*>(xg + (size_t)blockIdx.x * (A2 * INC * IND))[i];
        h4 h;
        h[0] = (_Float16)v[0]; h[1] = (_Float16)v[1];
        h[2] = (_Float16)v[2]; h[3] = (_Float16)v[3];
        *reinterpret_cast<h4*>(x_h + i * 4) = h;
    }
    __syncthreads();

    // ---- Phase H: hat for BOTH batch elements into registers; W loaded once ----
    h2 hA[72], hB[72];
    float s0A = 0.f, s0B = 0.f;
    {
        const WT* wp = Wg + ((size_t)(b * INC) * DC + d) * IND;
        const _Float16* xpA = x_h;
        const _Float16* xpB = x_h + INC * IND;
        #pragma unroll
        for (int c = 0; c < INC; ++c) {
            H8 xa, xb;
            xa.v = *reinterpret_cast<const h8*>(xpA + c * IND);
            xb.v = *reinterpret_cast<const h8*>(xpB + c * IND);
            float accA, accB;
            if constexpr (sizeof(WT) == 2) {
                H8 wv;
                wv.v = *reinterpret_cast<const h8*>(wp + (size_t)c * (DC * IND));
                accA = fdot2(wv.p[0], xa.p[0], 0.f);
                accA = fdot2(wv.p[1], xa.p[1], accA);
                accA = fdot2(wv.p[2], xa.p[2], accA);
                accA = fdot2(wv.p[3], xa.p[3], accA);
                accB = fdot2(wv.p[0], xb.p[0], 0.f);
                accB = fdot2(wv.p[1], xb.p[1], accB);
                accB = fdot2(wv.p[2], xb.p[2], accB);
                accB = fdot2(wv.p[3], xb.p[3], accB);
            } else {
                const float* wf = reinterpret_cast<const float*>(wp) + (size_t)c * (DC * IND);
                f4 w0 = *reinterpret_cast<const f4*>(wf);
                f4 w1 = *reinterpret_cast<const f4*>(wf + 4);
                accA = (float)xa.v[0] * w0[0];
                accB = (float)xb.v[0] * w0[0];
                accA = fmaf((float)xa.v[1], w0[1], accA);
                accB = fmaf((float)xb.v[1], w0[1], accB);
                accA = fmaf((float)xa.v[2], w0[2], accA);
                accB = fmaf((float)xb.v[2], w0[2], accB);
                accA = fmaf((float)xa.v[3], w0[3], accA);
                accB = fmaf((float)xb.v[3], w0[3], accB);
                accA = fmaf((float)xa.v[4], w1[0], accA);
                accB = fmaf((float)xb.v[4], w1[0], accB);
                accA = fmaf((float)xa.v[5], w1[1], accA);
                accB = fmaf((float)xb.v[5], w1[1], accB);
                accA = fmaf((float)xa.v[6], w1[2], accA);
                accB = fmaf((float)xb.v[6], w1[2], accB);
                accA = fmaf((float)xa.v[7], w1[3], accA);
                accB = fmaf((float)xb.v[7], w1[3], accB);
            }
            s0A += accA;
            s0B += accB;
            hA[c >> 1][c & 1] = (_Float16)accA;  // RN convert = single source of truth
            hB[c >> 1][c & 1] = (_Float16)accB;
        }
    }
    const float oA = squash16(s0A * (1.0f / 32.0f));  // softmax(0) uniform -> s0 free
    const float oB = squash16(s0B * (1.0f / 32.0f));

    // ---- route a0 then a1 (shared LDS hat; publish syncs make the handoff safe) ----
    route_one(hA, oA, hat, lg, o_h, out, blockIdx.x * A2 + 0, t, b, d);
    route_one(hB, oB, hat, lg, o_h, out, blockIdx.x * A2 + 1, t, b, d);
}

extern "C" void kernel_launch(void* const* d_in, const int* in_sizes, int n_in,
                              void* d_out, int out_size, void* d_ws, size_t ws_size,
                              hipStream_t stream) {
    const float* x = (const float*)d_in[0];
    const float* W = (const float*)d_in[1];
    float* out = (float*)d_out;

    const size_t WH_BYTES = (size_t)NC * INC * DC * IND * 2;  // 1179648

    if (ws_size >= WH_BYTES) {
        _Float16* Wh = (_Float16*)d_ws;
        hipLaunchKernelGGL(convw_kernel, dim3((NC * INC * DC * IND / 4) / 256),
                           dim3(256), 0, stream, W, Wh);
        hipFuncSetAttribute(reinterpret_cast<const void*>(&caps_kernel<_Float16>),
                            hipFuncAttributeMaxDynamicSharedMemorySize, SMEM_BYTES);
        hipLaunchKernelGGL(caps_kernel<_Float16>, dim3(512 / A2), dim3(NT), SMEM_BYTES,
                           stream, x, Wh, out);
    } else {
        hipFuncSetAttribute(reinterpret_cast<const void*>(&caps_kernel<float>),
                            hipFuncAttributeMaxDynamicSharedMemorySize, SMEM_BYTES);
        hipLaunchKernelGGL(caps_kernel<float>, dim3(512 / A2), dim3(NT), SMEM_BYTES,
                           stream, x, W, out);
    }
}